// Round 11
// baseline (163.225 us; speedup 1.0000x reference)
//
#include <hip/hip_runtime.h>

// (B,C,L,H,W) = (4,64,16,32,32), K=1024, D=C=64
constexpr int Cc   = 64;
constexpr int Kc   = 1024;
constexpr int Dc   = 64;
constexpr int LHWc = 16 * 32 * 32;        // 16384
constexpr int Nc   = 4 * LHWc;            // 65536 vectors
constexpr int QSIZE    = 4 * Cc * LHWc;   // 4194304
constexpr int OFF_LOSS = QSIZE;           // 4194304
constexpr int OFF_IDX  = QSIZE + 1;       // 4194305

constexpr int BLK_ROWS = 256;             // rows per block (16 MFMA tiles)
constexpr int NW       = 8;               // waves per block (512 threads)

typedef __attribute__((ext_vector_type(8))) short short8;   // 8 x bf16 bits
typedef __attribute__((ext_vector_type(4))) float f32x4;

static __device__ __forceinline__ unsigned short f2bf(float f) {
    unsigned u = __float_as_uint(f);
    u += 0x7FFFu + ((u >> 16) & 1u);      // RNE (finite data only)
    return (unsigned short)(u >> 16);
}
static __device__ __forceinline__ float bf2f(unsigned short h) {
    return __uint_as_float(((unsigned)h) << 16);
}

// Prep: zero loss; codebook bf16 hi/lo split; c2 (exact chain) and
// c2n = -0.5*(c2+0.25), the MFMA accumulator seed (score = dot + c2n, maximize).
__global__ __launch_bounds__(256) void vq_prep(
    const float* __restrict__ cb, float* __restrict__ out,
    unsigned short* __restrict__ cbh, unsigned short* __restrict__ cbl,
    float* __restrict__ c2, float* __restrict__ c2n)
{
    const int t  = threadIdx.x;
    const int k0 = blockIdx.x * 64;
    if (blockIdx.x == 0 && t == 0) out[OFF_LOSS] = 0.0f;

    const int d  = t & 63;
#pragma unroll
    for (int r = 0; r < 16; ++r) {
        const int k = k0 + r * 4 + (t >> 6);
        const float v = cb[(size_t)k * Dc + d];
        unsigned short h = f2bf(v);
        cbh[(size_t)k * Dc + d] = h;
        cbl[(size_t)k * Dc + d] = f2bf(v - bf2f(h));
    }
    if (t < 64) {
        const int k = k0 + t;
        const float* c = cb + (size_t)k * Dc;
        float s = 0.f;
#pragma unroll
        for (int dd = 0; dd < Dc; ++dd) s = __builtin_fmaf(c[dd], c[dd], s);
        c2[k]  = s;
        c2n[k] = -0.5f * (s + 0.25f);
    }
}

// r10 structure (2-tile ILP, codebook-stationary, 16-candidate recheck) with
// the recheck fixed to the REFERENCE ROUNDING GRID: d2 = fl(fma(-2,a,x2)+c2),
// compared by f32 bits with lowest-k ties. The codebook is uniform(+-1/1024),
// so d2's k-dependent part (~1e-2 spread) is quantized by the x2+c2 (~64)
// additions to ulp(64)=7.6e-6 -> ~0.2% of rows have the top-2 in the SAME
// f32 bucket; the reference argmin resolves those by lowest k. Any ranking
// on a finer grid (r10: c2-2dot, ulp~1e-9) breaks those ties by value ->
// hundreds of wrong indices. The in-loop fine-proxy top-2 is safe only as a
// candidate GENERATOR (a coarse-tie partner is at worst fine-2nd in its wave).
__global__ __launch_bounds__(512, 2) void vq_main(
    const float* __restrict__ in, const float* __restrict__ codebook,
    const unsigned short* __restrict__ cbh,
    const unsigned short* __restrict__ cbl,
    const float* __restrict__ c2g, const float* __restrict__ c2ng,
    float* __restrict__ out)
{
    __shared__ short8   xfh[2048];             // 32768 B: X frags hi
    __shared__ short8   xfl[2048];             // 32768 B: X frags lo
    __shared__ unsigned cK[NW][BLK_ROWS];      //  8192 B: per-wave k1|k2<<16
    __shared__ unsigned kwin[BLK_ROWS];        //  1024 B   (total 74752 B)

    const int tid  = threadIdx.x;
    const int lane = tid & 63;
    const int w    = __builtin_amdgcn_readfirstlane(tid >> 6);  // 0..7
    const int col  = lane & 15;
    const int g    = lane >> 4;

    const int bq = blockIdx.x >> 6;                    // batch (64 blk/batch)
    const int p0 = (blockIdx.x & 63) * BLK_ROWS;       // LHW offset
    const size_t inBase = (size_t)bq * (Cc * LHWc) + p0;

    // ---- this wave's 128 codes as A-fragments + c2n seeds (registers) ----
    short8 Ah[8][2], Al[8][2];
    f32x4  seed[8];
#pragma unroll
    for (int ct = 0; ct < 8; ++ct) {
        const size_t cb0 = (size_t)(w * 128 + ct * 16 + col) * Dc + g * 8;
#pragma unroll
        for (int kt = 0; kt < 2; ++kt) {
            Ah[ct][kt] = *(const short8*)(cbh + cb0 + kt * 32);
            Al[ct][kt] = *(const short8*)(cbl + cb0 + kt * 32);
        }
        seed[ct] = *(const f32x4*)&c2ng[w * 128 + ct * 16 + g * 4];
    }

    // ---- build X fragments straight from global (4 chunks/thread) ----
#pragma unroll
    for (int j = 0; j < 4; ++j) {
        const int c  = tid + j * 512;          // chunk = t*128 + kt*64 + gi*16 + cl
        const int t  = c >> 7;
        const int kt = (c >> 6) & 1;
        const int gi = (c >> 4) & 3;
        const int cl = c & 15;
        const int row = t * 16 + cl;
        const float* xp = in + inBase + (size_t)(kt * 32 + gi * 8) * LHWc + row;
        float v[8];
#pragma unroll
        for (int e = 0; e < 8; ++e) v[e] = xp[(size_t)e * LHWc];
        short8 h8, l8;
#pragma unroll
        for (int e = 0; e < 8; ++e) {
            unsigned short hv = f2bf(v[e]);
            h8[e] = (short)hv;
            l8[e] = (short)f2bf(v[e] - bf2f(hv));
        }
        xfh[c] = h8; xfl[c] = l8;
    }
    __syncthreads();

    // ---- main loop: 8 iterations x 2 interleaved tiles ----
#pragma unroll 1
    for (int tp = 0; tp < 8; ++tp) {
        const int b0 = tp * 256;               // tile 2*tp
        const int b1 = tp * 256 + 128;         // tile 2*tp+1
        const short8 xh0a = xfh[b0 + lane],      xh1a = xfh[b0 + 64 + lane];
        const short8 xl0a = xfl[b0 + lane],      xl1a = xfl[b0 + 64 + lane];
        const short8 xh0b = xfh[b1 + lane],      xh1b = xfh[b1 + 64 + lane];
        const short8 xl0b = xfl[b1 + lane],      xl1b = xfl[b1 + 64 + lane];

        float bV0 = -3.4e38f, sV0 = -3.4e38f, bV1 = -3.4e38f, sV1 = -3.4e38f;
        int   bK0 = 0, sK0 = 0, bK1 = 0, sK1 = 0;

#pragma unroll
        for (int ct = 0; ct < 8; ++ct) {
            f32x4 a0 = seed[ct];
            f32x4 a1 = seed[ct];
            a0 = __builtin_amdgcn_mfma_f32_16x16x32_bf16(Ah[ct][0], xh0a, a0, 0, 0, 0);
            a1 = __builtin_amdgcn_mfma_f32_16x16x32_bf16(Ah[ct][0], xh0b, a1, 0, 0, 0);
            a0 = __builtin_amdgcn_mfma_f32_16x16x32_bf16(Ah[ct][1], xh1a, a0, 0, 0, 0);
            a1 = __builtin_amdgcn_mfma_f32_16x16x32_bf16(Ah[ct][1], xh1b, a1, 0, 0, 0);
            a0 = __builtin_amdgcn_mfma_f32_16x16x32_bf16(Ah[ct][0], xl0a, a0, 0, 0, 0);
            a1 = __builtin_amdgcn_mfma_f32_16x16x32_bf16(Ah[ct][0], xl0b, a1, 0, 0, 0);
            a0 = __builtin_amdgcn_mfma_f32_16x16x32_bf16(Ah[ct][1], xl1a, a0, 0, 0, 0);
            a1 = __builtin_amdgcn_mfma_f32_16x16x32_bf16(Ah[ct][1], xl1b, a1, 0, 0, 0);
            a0 = __builtin_amdgcn_mfma_f32_16x16x32_bf16(Al[ct][0], xh0a, a0, 0, 0, 0);
            a1 = __builtin_amdgcn_mfma_f32_16x16x32_bf16(Al[ct][0], xh0b, a1, 0, 0, 0);
            a0 = __builtin_amdgcn_mfma_f32_16x16x32_bf16(Al[ct][1], xh1a, a0, 0, 0, 0);
            a1 = __builtin_amdgcn_mfma_f32_16x16x32_bf16(Al[ct][1], xh1b, a1, 0, 0, 0);
#pragma unroll
            for (int r = 0; r < 4; ++r) {
                const int k = w * 128 + ct * 16 + g * 4 + r;
                {   // tile A top-2 (maximize score = dot + c2n)
                    const float a = a0[r];
                    const float ob = bV0; const int obk = bK0;
                    const bool c1 = a > ob;
                    const bool c2_ = a > sV0;
                    bV0 = c1 ? a : ob;
                    sV0 = fmaxf(fminf(a, ob), sV0);      // median -> v_med3
                    bK0 = c1 ? k : obk;
                    sK0 = c2_ ? (c1 ? obk : k) : sK0;
                }
                {   // tile B top-2
                    const float a = a1[r];
                    const float ob = bV1; const int obk = bK1;
                    const bool c1 = a > ob;
                    const bool c2_ = a > sV1;
                    bV1 = c1 ? a : ob;
                    sV1 = fmaxf(fminf(a, ob), sV1);
                    bK1 = c1 ? k : obk;
                    sK1 = c2_ ? (c1 ? obk : k) : sK1;
                }
            }
        }

        // butterfly over g (lanes ^16, ^32), both tiles
#pragma unroll
        for (int m = 16; m <= 32; m <<= 1) {
            {
                float ob  = __shfl_xor(bV0, m, 64);
                int   obk = __shfl_xor(bK0, m, 64);
                float os  = __shfl_xor(sV0, m, 64);
                int   osk = __shfl_xor(sK0, m, 64);
                bool  c1 = ob > bV0;
                float nb  = c1 ? ob : bV0;
                int   nbk = c1 ? obk : bK0;
                float mn  = c1 ? bV0 : ob;
                int   mnk = c1 ? bK0 : obk;
                bool  c3 = os > sV0;
                float ms  = c3 ? os : sV0;
                int   msk = c3 ? osk : sK0;
                bool  c4 = mn > ms;
                sV0 = c4 ? mn : ms;  sK0 = c4 ? mnk : msk;
                bV0 = nb;            bK0 = nbk;
            }
            {
                float ob  = __shfl_xor(bV1, m, 64);
                int   obk = __shfl_xor(bK1, m, 64);
                float os  = __shfl_xor(sV1, m, 64);
                int   osk = __shfl_xor(sK1, m, 64);
                bool  c1 = ob > bV1;
                float nb  = c1 ? ob : bV1;
                int   nbk = c1 ? obk : bK1;
                float mn  = c1 ? bV1 : ob;
                int   mnk = c1 ? bK1 : obk;
                bool  c3 = os > sV1;
                float ms  = c3 ? os : sV1;
                int   msk = c3 ? osk : sK1;
                bool  c4 = mn > ms;
                sV1 = c4 ? mn : ms;  sK1 = c4 ? mnk : msk;
                bV1 = nb;            bK1 = nbk;
            }
        }
        if (g == 0) {
            cK[w][tp * 32 + col]      = (unsigned)bK0 | ((unsigned)sK0 << 16);
            cK[w][tp * 32 + 16 + col] = (unsigned)bK1 | ((unsigned)sK1 << 16);
        }
    }
    __syncthreads();

    // ---- exact recheck of ALL 16 wave-local top-2 candidates per row ----
    // Reference-grid scoring: d2 = fl(fma(-2,a,x2) + c2), f32-bit compare,
    // lowest-k ties. x2 via the ascending exact fma chain (as r5-r9).
    {
        const int row = tid >> 1;
        const int h   = tid & 1;               // handles waves h*4 .. h*4+3
        float x[64];
        const float* xr = in + inBase + row;
#pragma unroll
        for (int d = 0; d < 64; ++d) x[d] = xr[(size_t)d * LHWc];

        float x2 = 0.f;
#pragma unroll
        for (int d = 0; d < 64; ++d) x2 = __builtin_fmaf(x[d], x[d], x2);

        unsigned long long best = ~0ull;
#pragma unroll
        for (int wv = 0; wv < 4; ++wv) {
            const unsigned ks = cK[h * 4 + wv][row];
#pragma unroll
            for (int ci = 0; ci < 2; ++ci) {
                const int k = ci ? (int)(ks >> 16) : (int)(ks & 0xFFFFu);
                const float* cbr = codebook + (size_t)k * Dc;
                float a0 = 0.f, a1 = 0.f, a2 = 0.f, a3 = 0.f;
#pragma unroll
                for (int d = 0; d < 64; d += 4) {
                    a0 = __builtin_fmaf(x[d + 0], cbr[d + 0], a0);
                    a1 = __builtin_fmaf(x[d + 1], cbr[d + 1], a1);
                    a2 = __builtin_fmaf(x[d + 2], cbr[d + 2], a2);
                    a3 = __builtin_fmaf(x[d + 3], cbr[d + 3], a3);
                }
                const float a  = (a0 + a1) + (a2 + a3);
                const float d2 = __builtin_fmaf(-2.f, a, x2) + c2g[k];
                // d2 >= 0 -> float bits order-preserving as uint
                unsigned long long pk =
                    ((unsigned long long)__float_as_uint(d2) << 32) | (unsigned)k;
                best = pk < best ? pk : best;  // min d2, ties -> lowest k
            }
        }
        unsigned long long o = __shfl_xor(best, 1, 64);
        best = o < best ? o : best;
        if (h == 0) {
            const int kwinv = (int)(best & 0x3FFu);
            kwin[row] = (unsigned)kwinv;
            out[OFF_IDX + (size_t)blockIdx.x * BLK_ROWS + row] = (float)kwinv;
        }
    }
    __syncthreads();

    // ---- quantized write + loss: 2 threads/row, 32 channels each ----
    {
        const int row = tid & 255;
        const int cp  = tid >> 8;              // 0..1
        const int kw  = (int)kwin[row];
        const float* cbw = codebook + (size_t)kw * Dc + cp * 32;
        const float* xr  = in + inBase + row;
        float* qout = out + inBase + row;
        float ls = 0.f;
#pragma unroll
        for (int j = 0; j < 32; ++j) {
            const int c = cp * 32 + j;
            float qv = cbw[j];
            qout[(size_t)c * LHWc] = qv;       // coalesced across lanes per c
            float e = qv - xr[(size_t)c * LHWc];
            ls = __builtin_fmaf(e, e, ls);
        }
#pragma unroll
        for (int off = 32; off > 0; off >>= 1) ls += __shfl_down(ls, off, 64);
        if (lane == 0) atomicAdd(&out[OFF_LOSS], ls * (1.25f / (float)QSIZE));
    }
}

extern "C" void kernel_launch(void* const* d_in, const int* in_sizes, int n_in,
                              void* d_out, int out_size, void* d_ws, size_t ws_size,
                              hipStream_t stream) {
    const float* in = (const float*)d_in[0];   // [4,64,16,32,32] f32
    const float* cb = (const float*)d_in[1];   // [1024,64] f32
    float* out = (float*)d_out;
    (void)in_sizes; (void)n_in; (void)out_size; (void)ws_size;

    unsigned short* cbh = (unsigned short*)d_ws;                 // 128 KB
    unsigned short* cbl = cbh + (size_t)Kc * Dc;                 // 128 KB
    float*          c2  = (float*)(cbl + (size_t)Kc * Dc);       // 4 KB
    float*          c2n = c2 + Kc;                               // 4 KB

    vq_prep<<<dim3(16), dim3(256), 0, stream>>>(cb, out, cbh, cbl, c2, c2n);
    vq_main<<<dim3(Nc / BLK_ROWS), dim3(512), 0, stream>>>(in, cb, cbh, cbl, c2, c2n, out);
}